// Round 7
// baseline (228.493 us; speedup 1.0000x reference)
//
#include <hip/hip_runtime.h>
#include <hip/hip_bf16.h>

// GCNConv: out[i] = sum_{e: row[e]=i} dis[row]*dis[col]*xl[col] + dis[i]^2*xl[i]
// N=50000, E=1.6M, D=128, fp32 in/out.
//
// R21 -> R22: k_sortred2 postmortem: VGPR 68 crossed the 64-VGPR occupancy
// cliff (16.6% vs R16's 45%) -> HBM 28.7% vs 44%. The 16 extra VGPRs were
// the per-edge dis weights (na/nb). Fixes:
//  - k_hist first (256 blocks, LDS byte-packed col histogram -> phist),
//    k_dismerge -> dis; gemm epilogue premultiplies y = dis*(xW+b) so the
//    gather needs no weights (R16 structure restored exactly).
//  - k_sortred3: __launch_bounds__(512,8) pins VGPR<=64 (8 waves/SIMD);
//    cols broadcast-read from LDS sorted[] (no shfl); CFULL/CTAIL ping-pong.
//  - k_binjoint4 bin path: bcur atomic order rotated per block (bijective)
//    to break 196-block lock-step contention on the 782 bcur words.

#define D     128
#define TILE  8192
#define BINB  1024      // bin/gemm block size
#define RPB   64        // rows per bucket
#define CAPB  4096      // ebuf capacity per bucket (mean 2046, ~45 sigma)
#define MAXBK 1024      // bucket id fits 10 bits
#define NH    256       // histogram blocks

typedef short  bf16x8 __attribute__((ext_vector_type(8)));
typedef float  f32x4  __attribute__((ext_vector_type(4)));
typedef unsigned short us4 __attribute__((ext_vector_type(4)));
typedef unsigned short us8 __attribute__((ext_vector_type(8)));

static __device__ __forceinline__ unsigned short f2bf(float f) {
    unsigned u = __float_as_uint(f);
    u = (u + 0x7FFFu + ((u >> 16) & 1u)) >> 16;   // RNE
    return (unsigned short)u;
}
static __device__ __forceinline__ float bf2f(unsigned short s) {
    return __uint_as_float(((unsigned)s) << 16);
}

// --- init: bcur[b]=b*CAPB, wtb = bf16(W^T) -------------------------------
__global__ __launch_bounds__(256) void k_prep(const float* __restrict__ W,
                                              unsigned short* __restrict__ wtb,
                                              int* __restrict__ bcur,
                                              int NBK) {
    int i = blockIdx.x * 256 + threadIdx.x;
    if (i < NBK) bcur[i] = i * CAPB;
    if (i < D * D) {
        int n = i >> 7, k = i & 127;
        wtb[n * 128 + k] = f2bf(W[k * 128 + n]);
    }
}

// --- col-degree histogram: LDS byte-packed partials -> phist -------------
__global__ __launch_bounds__(1024) void k_hist(const int* __restrict__ cols,
                                               unsigned* __restrict__ phist,
                                               int E, int NW) {
    __shared__ unsigned hist[16384];             // 64 KB, NW <= 16384
    const int t = threadIdx.x;
    for (int w = t; w < NW; w += 1024) hist[w] = 0;
    __syncthreads();
    const int hb   = blockIdx.x;
    const int SEG  = (E + NH - 1) / NH;
    const int hbeg = hb * SEG;
    int hend = hbeg + SEG; if (hend > E) hend = E;
    for (int i = hbeg + t; i < hend; i += 1024) {
        unsigned c = (unsigned)cols[i];
        atomicAdd(&hist[c >> 2], 1u << ((c & 3u) * 8u));
    }
    __syncthreads();
    unsigned* dst = phist + (size_t)hb * NW;
    for (int w = t; w < NW; w += 1024) dst[w] = hist[w];
}

// --- merge NH partial histograms -> dis = rsqrt(deg+1) -------------------
__global__ __launch_bounds__(256) void k_dismerge(const unsigned* __restrict__ phist,
                                                  float* __restrict__ dis,
                                                  int N, int NW) {
    int w = blockIdx.x * 256 + threadIdx.x;
    if (w >= NW) return;
    unsigned s0 = 0, s1 = 0, s2 = 0, s3 = 0;
    const unsigned* pw = phist + w;
    #pragma unroll 8
    for (int b = 0; b < NH; ++b) {
        unsigned u = pw[(size_t)b * NW];
        s0 += u & 255u;
        s1 += (u >> 8) & 255u;
        s2 += (u >> 16) & 255u;
        s3 += u >> 24;
    }
    int c0 = w * 4;
    float4 o = make_float4(rsqrtf((float)(s0 + 1)), rsqrtf((float)(s1 + 1)),
                           rsqrtf((float)(s2 + 1)), rsqrtf((float)(s3 + 1)));
    if (c0 + 3 < N) {
        *(float4*)&dis[c0] = o;
    } else {
        if (c0     < N) dis[c0]     = o.x;
        if (c0 + 1 < N) dis[c0 + 1] = o.y;
        if (c0 + 2 < N) dis[c0 + 2] = o.z;
        if (c0 + 3 < N) dis[c0 + 3] = o.w;
    }
}

// --- fused: blocks [0,NT) bin edges (row-bucket LDS sort -> ebuf);
//     blocks [NT,NT+GN) MFMA gemm, epilogue xlb = bf16(dis*(xW+b)) --------
__global__ __launch_bounds__(1024) void k_binjoint4(
        const int* __restrict__ rows, const int* __restrict__ cols,
        int* __restrict__ bcur, unsigned* __restrict__ ebuf,
        const float* __restrict__ x, const unsigned short* __restrict__ wtb,
        const float* __restrict__ bia, const float* __restrict__ dis,
        unsigned short* __restrict__ xlb,
        int E, int N, int NBK, int NT) {
    __shared__ __align__(16) unsigned char smem[65536];
    const int t = threadIdx.x;

    if ((int)blockIdx.x >= NT) {
        // ---------------- gemm path: 64x128 tile, waves 0-3 compute ------
        unsigned short (*wt)[136] = (unsigned short (*)[136])smem;            // 34816 B
        unsigned short (*xs)[136] = (unsigned short (*)[136])(smem + 34816);  // 17408 B
        const int row0 = ((int)blockIdx.x - NT) * 64;
        #pragma unroll
        for (int i = 0; i < 2; ++i) {         // W^T: 2048 ushort8 chunks
            int j = i * 1024 + t;
            int n = j >> 4, k8 = j & 15;
            us8 v = *(const us8*)&wtb[j * 8];
            *(us8*)&wt[n][k8 * 8] = v;
        }
        #pragma unroll
        for (int i = 0; i < 2; ++i) {         // x: 2048 float4 -> ushort4
            int j = i * 1024 + t;
            int r = j >> 5, c4 = j & 31;
            int gr = row0 + r;
            us4 o = (us4){0, 0, 0, 0};
            if (gr < N) {
                float4 v = *(const float4*)&x[(size_t)gr * D + c4 * 4];
                o = (us4){f2bf(v.x), f2bf(v.y), f2bf(v.z), f2bf(v.w)};
            }
            *(us4*)&xs[r][c4 * 4] = o;
        }
        __syncthreads();
        if (t < 256) {
            const int w  = t >> 6, l = t & 63;
            const int m0 = w * 16;
            const int lm = l & 15, lq = l >> 4;
            f32x4 acc[8];
            #pragma unroll
            for (int nt = 0; nt < 8; ++nt) acc[nt] = (f32x4){0.f, 0.f, 0.f, 0.f};
            #pragma unroll
            for (int kk = 0; kk < 4; ++kk) {
                const int kof = kk * 32 + lq * 8;
                bf16x8 a = *(const bf16x8*)&xs[m0 + lm][kof];
                #pragma unroll
                for (int nt = 0; nt < 8; ++nt) {
                    bf16x8 bb = *(const bf16x8*)&wt[nt * 16 + lm][kof];
                    acc[nt] = __builtin_amdgcn_mfma_f32_16x16x32_bf16(a, bb, acc[nt], 0, 0, 0);
                }
            }
            float bc[8];
            #pragma unroll
            for (int nt = 0; nt < 8; ++nt) bc[nt] = bia[nt * 16 + lm];
            #pragma unroll
            for (int r = 0; r < 4; ++r) {
                int grow = row0 + m0 + lq * 4 + r;
                if (grow < N) {
                    float dv = dis[grow];
                    #pragma unroll
                    for (int nt = 0; nt < 8; ++nt)
                        xlb[(size_t)grow * D + nt * 16 + lm] = f2bf(dv * (acc[nt][r] + bc[nt]));
                }
            }
        }
        return;
    }

    // ---------------- bin path: row-bucket LDS sort, coalesced writes ----
    unsigned* sorted = (unsigned*)smem;                 // 32768 B
    int* lcnt  = (int*)(smem + 32768);                  // 800 ints each
    int* lbase = lcnt + 800;
    int* excl  = lcnt + 1600;
    int* cur   = lcnt + 2400;                           // ends at 45568 B

    const int base = blockIdx.x * TILE;
    int m = E - base; if (m > TILE) m = TILE;

    unsigned p[TILE / BINB];
    #pragma unroll
    for (int it = 0; it < TILE / BINB; ++it) {
        int i = it * BINB + t;
        if (i < m) {
            unsigned r = (unsigned)rows[base + i];
            unsigned c = (unsigned)cols[base + i];
            p[it] = c | ((r & 63u) << 16) | ((r >> 6) << 22);
        }
    }
    if (t < 800) lcnt[t] = 0;
    __syncthreads();
    #pragma unroll
    for (int it = 0; it < TILE / BINB; ++it) {
        int i = it * BINB + t;
        if (i < m) atomicAdd(&lcnt[p[it] >> 22], 1);
    }
    __syncthreads();
    // wave 0: scan 782 buckets, 13 keys/lane; write excl AND cur
    if (t < 64) {
        int v[13], s = 0;
        #pragma unroll
        for (int u = 0; u < 13; ++u) {
            int k = t * 13 + u;
            v[u] = (k < NBK) ? lcnt[k] : 0;
            s += v[u];
        }
        int inc = s;
        #pragma unroll
        for (int off = 1; off < 64; off <<= 1) { int o = __shfl_up(inc, off); if (t >= off) inc += o; }
        int run = inc - s;
        #pragma unroll
        for (int u = 0; u < 13; ++u) {
            int k = t * 13 + u;
            if (k < NBK) { excl[k] = run; cur[k] = run; }
            run += v[u];
        }
    }
    if (t < NBK) {                   // reserve global regions, rotated order
        int tb = t + (int)((blockIdx.x * 331u) % (unsigned)NBK);
        if (tb >= NBK) tb -= NBK;
        int c0 = lcnt[tb];
        lbase[tb] = c0 ? atomicAdd(&bcur[tb], c0) : 0;
    }
    __syncthreads();
    #pragma unroll
    for (int it = 0; it < TILE / BINB; ++it) {   // scatter into LDS (random: free)
        int i = it * BINB + t;
        if (i < m) {
            int pos = atomicAdd(&cur[p[it] >> 22], 1);
            sorted[pos] = p[it];
        }
    }
    __syncthreads();
    #pragma unroll
    for (int it = 0; it < TILE / BINB; ++it) {   // positional coalesced writes
        int i = it * BINB + t;
        if (i < m) {
            unsigned pp = sorted[i];
            int bk = pp >> 22;
            int g  = lbase[bk] + i - excl[bk];
            if (g < (bk + 1) * CAPB) ebuf[g] = pp & 0x3FFFFFu;  // col | rl<<16
        }
    }
}

// --- block-per-bucket: LDS counting sort by row-local, then R16-exact
//     premul gather. xlb holds y = dis*xl. out = dis_i*(y_i + sum y_c). ---
__global__ __launch_bounds__(512, 8) void k_sortred3(
        const int* __restrict__ bcur, const unsigned* __restrict__ ebuf,
        const float* __restrict__ dis, const unsigned short* __restrict__ xlb,
        float* __restrict__ out, int N) {
    __shared__ unsigned short sorted[CAPB];     // 8 KB
    __shared__ int cnt[RPB];
    __shared__ int excl[RPB];
    __shared__ int cur[RPB];
    const int t = threadIdx.x, b = blockIdx.x;
    const int ebase = b * CAPB;
    int mb = bcur[b] - ebase;
    if (mb > CAPB) mb = CAPB;
    if (mb < 0) mb = 0;

    unsigned p[CAPB / 512];                     // 8 regs (dead after prologue)
    #pragma unroll
    for (int it = 0; it < CAPB / 512; ++it) {
        int i = it * 512 + t;
        p[it] = (i < mb) ? ebuf[ebase + i] : 0xFFFFFFFFu;
    }
    if (t < RPB) cnt[t] = 0;
    __syncthreads();
    #pragma unroll
    for (int it = 0; it < CAPB / 512; ++it)
        if (p[it] != 0xFFFFFFFFu) atomicAdd(&cnt[(p[it] >> 16) & 63], 1);
    __syncthreads();
    if (t < 64) {                               // 64-key wave scan
        int v = cnt[t], inc = v;
        #pragma unroll
        for (int off = 1; off < 64; off <<= 1) { int o = __shfl_up(inc, off); if (t >= off) inc += o; }
        excl[t] = inc - v;
        cur[t]  = inc - v;
    }
    __syncthreads();
    #pragma unroll
    for (int it = 0; it < CAPB / 512; ++it)     // scatter (random LDS: free)
        if (p[it] != 0xFFFFFFFFu) {
            int pos = atomicAdd(&cur[(p[it] >> 16) & 63], 1);
            sorted[pos] = (unsigned short)(p[it] & 0xFFFFu);
        }
    __syncthreads();

    const int wv = t >> 6, lane = t & 63;
    const int half = lane >> 5, l32 = lane & 31;

#define FETCH(V, J) do { \
    _Pragma("unroll") \
    for (int u = 0; u < 8; ++u) { \
        int idx = (J) + 2 * u + half; \
        int cc = sorted[beg + (idx < m ? idx : 0)]; \
        V[u] = *(const us4*)&xlb[((size_t)cc << 7) + (l32 << 2)]; \
    } } while (0)
#define CFULL(V) do { \
    _Pragma("unroll") \
    for (int u = 0; u < 8; ++u) { \
        a0 += bf2f(V[u][0]); a1 += bf2f(V[u][1]); \
        a2 += bf2f(V[u][2]); a3 += bf2f(V[u][3]); \
    } } while (0)
#define CTAIL(V, J) do { \
    _Pragma("unroll") \
    for (int u = 0; u < 8; ++u) { \
        float w = ((J) + 2 * u + half < m) ? 1.0f : 0.0f; \
        a0 = fmaf(w, bf2f(V[u][0]), a0); a1 = fmaf(w, bf2f(V[u][1]), a1); \
        a2 = fmaf(w, bf2f(V[u][2]), a2); a3 = fmaf(w, bf2f(V[u][3]), a3); \
    } } while (0)

    // gather: wave wv owns rows wv*8 .. wv*8+7
    for (int r8 = 0; r8 < 8; ++r8) {
        const int rl = wv * 8 + r8;
        const int grow = b * RPB + rl;
        if (grow >= N) break;
        const int beg = excl[rl];
        const int m = cur[rl] - beg;
        // self loop: y[i]; only half 0 contributes (halves summed at end)
        us4 sv = *(const us4*)&xlb[(size_t)grow * D + (l32 << 2)];
        float s = (half == 0) ? 1.0f : 0.0f;
        float a0 = s * bf2f(sv[0]), a1 = s * bf2f(sv[1]);
        float a2 = s * bf2f(sv[2]), a3 = s * bf2f(sv[3]);
        if (m > 0) {
            us4 A[8], B[8];
            int j = 0;
            FETCH(A, 0);
            for (; j + 32 <= m; j += 32) {
                FETCH(B, j + 16);               // issue next before consuming A
                CFULL(A);
                if (j + 32 < m) FETCH(A, j + 32);
                CFULL(B);
            }
            int rem = m - j;                    // 0 < rem < 32 => A fetched at j
            if (rem > 0) {
                if (rem > 16) { FETCH(B, j + 16); CFULL(A); CTAIL(B, j + 16); }
                else          { CTAIL(A, j); }
            }
        }
        a0 += __shfl_xor(a0, 32);
        a1 += __shfl_xor(a1, 32);
        a2 += __shfl_xor(a2, 32);
        a3 += __shfl_xor(a3, 32);
        if (half == 0) {
            const float di = dis[grow];
            *(float4*)&out[(size_t)grow * D + (l32 << 2)] =
                make_float4(di * a0, di * a1, di * a2, di * a3);
        }
    }
#undef FETCH
#undef CFULL
#undef CTAIL
}

// ======================= fallback (R1 atomic path) =======================
__global__ __launch_bounds__(256) void k_zero(int* __restrict__ p, int n) {
    int i = blockIdx.x * 256 + threadIdx.x;
    if (i < n) p[i] = 0;
}
__global__ __launch_bounds__(256) void k_deg(const int* __restrict__ cols,
                                             int* __restrict__ cntc, int E) {
    int e = blockIdx.x * 256 + threadIdx.x;
    if (e < E) atomicAdd(&cntc[cols[e]], 1);
}
__global__ __launch_bounds__(256) void k_dis(const int* __restrict__ cntc,
                                             float* __restrict__ dis, int N) {
    int i = blockIdx.x * 256 + threadIdx.x;
    if (i < N) dis[i] = rsqrtf((float)(cntc[i] + 1));
}
#define GEMM_R 8
__global__ __launch_bounds__(128) void k_gemmf(const float* __restrict__ x,
                                               const float* __restrict__ W,
                                               const float* __restrict__ b,
                                               float* __restrict__ xl, int N) {
    __shared__ float xs[GEMM_R][D];
    const int c  = threadIdx.x;
    const int r0 = blockIdx.x * GEMM_R;
    #pragma unroll
    for (int r = 0; r < GEMM_R; ++r) {
        int row = r0 + r;
        xs[r][c] = (row < N) ? x[row * D + c] : 0.0f;
    }
    __syncthreads();
    float acc[GEMM_R];
    const float bc = b[c];
    #pragma unroll
    for (int r = 0; r < GEMM_R; ++r) acc[r] = bc;
    for (int k = 0; k < D; k += 4) {
        const float w0 = W[(k + 0) * D + c];
        const float w1 = W[(k + 1) * D + c];
        const float w2 = W[(k + 2) * D + c];
        const float w3 = W[(k + 3) * D + c];
        #pragma unroll
        for (int r = 0; r < GEMM_R; ++r) {
            const float4 xv = *reinterpret_cast<const float4*>(&xs[r][k]);
            acc[r] = fmaf(xv.x, w0, acc[r]);
            acc[r] = fmaf(xv.y, w1, acc[r]);
            acc[r] = fmaf(xv.z, w2, acc[r]);
            acc[r] = fmaf(xv.w, w3, acc[r]);
        }
    }
    #pragma unroll
    for (int r = 0; r < GEMM_R; ++r) {
        int row = r0 + r;
        if (row < N) xl[row * D + c] = acc[r];
    }
}
__global__ __launch_bounds__(256) void k_self(const float* __restrict__ xl,
                                              const float* __restrict__ dis,
                                              float* __restrict__ out, int N) {
    int gid = blockIdx.x * 256 + threadIdx.x;
    int i = gid >> 7;
    if (i < N) {
        float d = dis[i];
        out[gid] = d * d * xl[gid];
    }
}
__global__ __launch_bounds__(256) void k_scatter(const int* __restrict__ rows,
                                                 const int* __restrict__ cols,
                                                 const float* __restrict__ dis,
                                                 const float* __restrict__ xl,
                                                 float* __restrict__ out, int E) {
    long long gid = (long long)blockIdx.x * 256 + threadIdx.x;
    int e    = (int)(gid >> 6);
    int lane = (int)(gid & 63);
    if (e >= E) return;
    const int row = rows[e];
    const int col = cols[e];
    const float nrm = dis[row] * dis[col];
    atomicAdd(&out[row * D + lane],      nrm * xl[col * D + lane]);
    atomicAdd(&out[row * D + 64 + lane], nrm * xl[col * D + 64 + lane]);
}

// ======================= launch ==========================================
extern "C" void kernel_launch(void* const* d_in, const int* in_sizes, int n_in,
                              void* d_out, int out_size, void* d_ws, size_t ws_size,
                              hipStream_t stream) {
    const float* x   = (const float*)d_in[0];
    const int*   ei  = (const int*)d_in[1];
    const float* W   = (const float*)d_in[2];
    const float* b   = (const float*)d_in[3];
    float*       out = (float*)d_out;

    const int N = in_sizes[0] / D;   // 50000
    const int E = in_sizes[1] / 2;   // 1.6M
    const int* rows = ei;
    const int* cols = ei + E;
    const int NBK = (N + RPB - 1) / RPB;       // 782 buckets of 64 rows
    const int NT  = (E + TILE - 1) / TILE;     // 196 bin blocks
    const int GN  = (N + 63) / 64;             // 782 gemm blocks
    const int NW  = (N + 3) / 4;               // 12500 histogram words

    // ws layout
    char* p = (char*)d_ws;
    size_t off = 0;
    unsigned short* xlb     = (unsigned short*)(p + off); off += (size_t)N * D * 2;
    unsigned short* wtb     = (unsigned short*)(p + off); off += (size_t)D * D * 2;
    float*          dis     = (float*)(p + off);          off += (size_t)N * 4;
    int*            bcur    = (int*)(p + off);            off += (size_t)MAXBK * 4;
    unsigned*       ebuf    = (unsigned*)(p + off);       off += (size_t)NBK * CAPB * 4;
    unsigned*       phist   = (unsigned*)(p + off);       off += (size_t)NH * NW * 4;

    const int gN = (N + 255) / 256;
    const int gE = (E + 255) / 256;

    if (N <= 65536 && NBK <= MAXBK && NBK <= 800 && ws_size >= off) {
        int gP = (D * D + 255) / 256;
        if (gP < (NBK + 255) / 256) gP = (NBK + 255) / 256;
        k_prep     <<<gP, 256, 0, stream>>>(W, wtb, bcur, NBK);
        k_hist     <<<NH, 1024, 0, stream>>>(cols, phist, E, NW);
        k_dismerge <<<(NW + 255) / 256, 256, 0, stream>>>(phist, dis, N, NW);
        k_binjoint4<<<NT + GN, BINB, 0, stream>>>(rows, cols, bcur, ebuf,
                                                  x, wtb, b, dis, xlb,
                                                  E, N, NBK, NT);
        k_sortred3 <<<NBK, 512, 0, stream>>>(bcur, ebuf, dis, xlb, out, N);
    } else {
        // fallback: R1 atomic scatter path (fp32 xl)
        char* q = (char*)d_ws;
        float* xl   = (float*)q;
        float* disF = (float*)(q + (size_t)N * D * 4);
        int*   cc   = (int*)(q + (size_t)N * D * 4 + (size_t)N * 4);
        k_zero <<<gN, 256, 0, stream>>>(cc, N);
        k_deg  <<<gE, 256, 0, stream>>>(cols, cc, E);
        k_dis  <<<gN, 256, 0, stream>>>(cc, disF, N);
        k_gemmf<<<(N + GEMM_R - 1) / GEMM_R, 128, 0, stream>>>(x, W, b, xl, N);
        k_self <<<((N * D) + 255) / 256, 256, 0, stream>>>(xl, disF, out, N);
        long long st = (long long)E * 64;
        k_scatter<<<(int)((st + 255) / 256), 256, 0, stream>>>(rows, cols, disF, xl, out, E);
    }
}

// Round 8
// 184.987 us; speedup vs baseline: 1.2352x; 1.2352x over previous
//
#include <hip/hip_runtime.h>
#include <hip/hip_bf16.h>

// GCNConv: out[i] = sum_{e: row[e]=i} dis[row]*dis[col]*xl[col] + dis[i]^2*xl[i]
// N=50000, E=1.6M, D=128, fp32 in/out.
//
// R22 -> R23: sortred3 spilled (launch_bounds(512,8) forced VGPR<=64 under a
// ~68-reg body -> scratch: FETCH +120MB, WRITE +71MB, 110us). Fixes:
//  - k_sortred4: two-pass ebuf prologue (no p[] regs), R16-exact shfl gather
//    (no weights; premul in gemm epilogue), NO min-wave bound. ~50 VGPR.
//  - binjoint split into k_bin + k_gemm for per-kernel counters (binjoint
//    has been invisible at ~90us for 3 rounds).
//  - k_gemm epilogue: stage results in LDS, one us8 store/thread (was 32
//    scattered 2B stores/thread).

#define D     128
#define TILE  8192
#define BINB  1024      // bin block size
#define RPB   64        // rows per bucket
#define CAPB  4096      // ebuf capacity per bucket (mean 2046, ~45 sigma)
#define MAXBK 1024      // bucket id fits 10 bits
#define NH    256       // histogram blocks

typedef short  bf16x8 __attribute__((ext_vector_type(8)));
typedef float  f32x4  __attribute__((ext_vector_type(4)));
typedef unsigned short us4 __attribute__((ext_vector_type(4)));
typedef unsigned short us8 __attribute__((ext_vector_type(8)));

static __device__ __forceinline__ unsigned short f2bf(float f) {
    unsigned u = __float_as_uint(f);
    u = (u + 0x7FFFu + ((u >> 16) & 1u)) >> 16;   // RNE
    return (unsigned short)u;
}
static __device__ __forceinline__ float bf2f(unsigned short s) {
    return __uint_as_float(((unsigned)s) << 16);
}

// --- init: bcur[b]=b*CAPB, wtb = bf16(W^T) -------------------------------
__global__ __launch_bounds__(256) void k_prep(const float* __restrict__ W,
                                              unsigned short* __restrict__ wtb,
                                              int* __restrict__ bcur,
                                              int NBK) {
    int i = blockIdx.x * 256 + threadIdx.x;
    if (i < NBK) bcur[i] = i * CAPB;
    if (i < D * D) {
        int n = i >> 7, k = i & 127;
        wtb[n * 128 + k] = f2bf(W[k * 128 + n]);
    }
}

// --- col-degree histogram: LDS byte-packed partials -> phist -------------
__global__ __launch_bounds__(1024) void k_hist(const int* __restrict__ cols,
                                               unsigned* __restrict__ phist,
                                               int E, int NW) {
    __shared__ unsigned hist[16384];             // 64 KB, NW <= 16384
    const int t = threadIdx.x;
    for (int w = t; w < NW; w += 1024) hist[w] = 0;
    __syncthreads();
    const int hb   = blockIdx.x;
    const int SEG  = (E + NH - 1) / NH;
    const int hbeg = hb * SEG;
    int hend = hbeg + SEG; if (hend > E) hend = E;
    for (int i = hbeg + t; i < hend; i += 1024) {
        unsigned c = (unsigned)cols[i];
        atomicAdd(&hist[c >> 2], 1u << ((c & 3u) * 8u));
    }
    __syncthreads();
    unsigned* dst = phist + (size_t)hb * NW;
    for (int w = t; w < NW; w += 1024) dst[w] = hist[w];
}

// --- merge NH partial histograms -> dis = rsqrt(deg+1) -------------------
__global__ __launch_bounds__(256) void k_dismerge(const unsigned* __restrict__ phist,
                                                  float* __restrict__ dis,
                                                  int N, int NW) {
    int w = blockIdx.x * 256 + threadIdx.x;
    if (w >= NW) return;
    unsigned s0 = 0, s1 = 0, s2 = 0, s3 = 0;
    const unsigned* pw = phist + w;
    #pragma unroll 8
    for (int b = 0; b < NH; ++b) {
        unsigned u = pw[(size_t)b * NW];
        s0 += u & 255u;
        s1 += (u >> 8) & 255u;
        s2 += (u >> 16) & 255u;
        s3 += u >> 24;
    }
    int c0 = w * 4;
    float4 o = make_float4(rsqrtf((float)(s0 + 1)), rsqrtf((float)(s1 + 1)),
                           rsqrtf((float)(s2 + 1)), rsqrtf((float)(s3 + 1)));
    if (c0 + 3 < N) {
        *(float4*)&dis[c0] = o;
    } else {
        if (c0     < N) dis[c0]     = o.x;
        if (c0 + 1 < N) dis[c0 + 1] = o.y;
        if (c0 + 2 < N) dis[c0 + 2] = o.z;
        if (c0 + 3 < N) dis[c0 + 3] = o.w;
    }
}

// --- MFMA gemm 64x128; epilogue y = bf16(dis*(xW+b)) via LDS, us8 stores -
__global__ __launch_bounds__(1024) void k_gemm(
        const float* __restrict__ x, const unsigned short* __restrict__ wtb,
        const float* __restrict__ bia, const float* __restrict__ dis,
        unsigned short* __restrict__ xlb, int N) {
    __shared__ __align__(16) unsigned char smem[52224];
    unsigned short (*wt)[136] = (unsigned short (*)[136])smem;            // 34816 B
    unsigned short (*xs)[136] = (unsigned short (*)[136])(smem + 34816);  // 17408 B
    unsigned short (*ys)[128] = (unsigned short (*)[128])smem;            // 16384 B (over wt)
    const int t = threadIdx.x;
    const int row0 = blockIdx.x * 64;
    #pragma unroll
    for (int i = 0; i < 2; ++i) {         // W^T: 2048 ushort8 chunks
        int j = i * 1024 + t;
        int n = j >> 4, k8 = j & 15;
        us8 v = *(const us8*)&wtb[j * 8];
        *(us8*)&wt[n][k8 * 8] = v;
    }
    #pragma unroll
    for (int i = 0; i < 2; ++i) {         // x: 2048 float4 -> ushort4
        int j = i * 1024 + t;
        int r = j >> 5, c4 = j & 31;
        int gr = row0 + r;
        us4 o = (us4){0, 0, 0, 0};
        if (gr < N) {
            float4 v = *(const float4*)&x[(size_t)gr * D + c4 * 4];
            o = (us4){f2bf(v.x), f2bf(v.y), f2bf(v.z), f2bf(v.w)};
        }
        *(us4*)&xs[r][c4 * 4] = o;
    }
    __syncthreads();
    f32x4 acc[8];
    if (t < 256) {
        const int w  = t >> 6, l = t & 63;
        const int m0 = w * 16;
        const int lm = l & 15, lq = l >> 4;
        #pragma unroll
        for (int nt = 0; nt < 8; ++nt) acc[nt] = (f32x4){0.f, 0.f, 0.f, 0.f};
        #pragma unroll
        for (int kk = 0; kk < 4; ++kk) {
            const int kof = kk * 32 + lq * 8;
            bf16x8 a = *(const bf16x8*)&xs[m0 + lm][kof];
            #pragma unroll
            for (int nt = 0; nt < 8; ++nt) {
                bf16x8 bb = *(const bf16x8*)&wt[nt * 16 + lm][kof];
                acc[nt] = __builtin_amdgcn_mfma_f32_16x16x32_bf16(a, bb, acc[nt], 0, 0, 0);
            }
        }
    }
    __syncthreads();                      // all wt/xs reads complete
    if (t < 256) {
        const int w  = t >> 6, l = t & 63;
        const int m0 = w * 16;
        const int lm = l & 15, lq = l >> 4;
        float bc[8];
        #pragma unroll
        for (int nt = 0; nt < 8; ++nt) bc[nt] = bia[nt * 16 + lm];
        #pragma unroll
        for (int r = 0; r < 4; ++r) {
            int lrow = m0 + lq * 4 + r;
            int grow = row0 + lrow;
            float dv = (grow < N) ? dis[grow] : 0.0f;
            #pragma unroll
            for (int nt = 0; nt < 8; ++nt)
                ys[lrow][nt * 16 + lm] = f2bf(dv * (acc[nt][r] + bc[nt]));
        }
    }
    __syncthreads();
    {   // coalesced copy-out: 1024 threads x one us8 (64 rows x 128 cols)
        int r = t >> 4, e8 = t & 15;
        int grow = row0 + r;
        if (grow < N)
            *(us8*)&xlb[(size_t)grow * D + e8 * 8] = *(const us8*)&ys[r][e8 * 8];
    }
}

// --- bin edges: row-bucket LDS sort -> ebuf (coalesced 4B writes) --------
__global__ __launch_bounds__(1024) void k_bin(
        const int* __restrict__ rows, const int* __restrict__ cols,
        int* __restrict__ bcur, unsigned* __restrict__ ebuf,
        int E, int NBK) {
    __shared__ __align__(16) unsigned char smem[45568];
    unsigned* sorted = (unsigned*)smem;                 // 32768 B
    int* lcnt  = (int*)(smem + 32768);                  // 800 ints each
    int* lbase = lcnt + 800;
    int* excl  = lcnt + 1600;
    int* cur   = lcnt + 2400;                           // ends at 45568 B
    const int t = threadIdx.x;

    const int base = blockIdx.x * TILE;
    int m = E - base; if (m > TILE) m = TILE;

    unsigned p[TILE / BINB];
    #pragma unroll
    for (int it = 0; it < TILE / BINB; ++it) {
        int i = it * BINB + t;
        if (i < m) {
            unsigned r = (unsigned)rows[base + i];
            unsigned c = (unsigned)cols[base + i];
            p[it] = c | ((r & 63u) << 16) | ((r >> 6) << 22);
        }
    }
    if (t < 800) lcnt[t] = 0;
    __syncthreads();
    #pragma unroll
    for (int it = 0; it < TILE / BINB; ++it) {
        int i = it * BINB + t;
        if (i < m) atomicAdd(&lcnt[p[it] >> 22], 1);
    }
    __syncthreads();
    // wave 0: scan 782 buckets, 13 keys/lane; write excl AND cur
    if (t < 64) {
        int v[13], s = 0;
        #pragma unroll
        for (int u = 0; u < 13; ++u) {
            int k = t * 13 + u;
            v[u] = (k < NBK) ? lcnt[k] : 0;
            s += v[u];
        }
        int inc = s;
        #pragma unroll
        for (int off = 1; off < 64; off <<= 1) { int o = __shfl_up(inc, off); if (t >= off) inc += o; }
        int run = inc - s;
        #pragma unroll
        for (int u = 0; u < 13; ++u) {
            int k = t * 13 + u;
            if (k < NBK) { excl[k] = run; cur[k] = run; }
            run += v[u];
        }
    }
    if (t < NBK) {                   // reserve global regions, rotated order
        int tb = t + (int)((blockIdx.x * 331u) % (unsigned)NBK);
        if (tb >= NBK) tb -= NBK;
        int c0 = lcnt[tb];
        lbase[tb] = c0 ? atomicAdd(&bcur[tb], c0) : 0;
    }
    __syncthreads();
    #pragma unroll
    for (int it = 0; it < TILE / BINB; ++it) {   // scatter into LDS (random: free)
        int i = it * BINB + t;
        if (i < m) {
            int pos = atomicAdd(&cur[p[it] >> 22], 1);
            sorted[pos] = p[it];
        }
    }
    __syncthreads();
    #pragma unroll
    for (int it = 0; it < TILE / BINB; ++it) {   // positional coalesced writes
        int i = it * BINB + t;
        if (i < m) {
            unsigned pp = sorted[i];
            int bk = pp >> 22;
            int g  = lbase[bk] + i - excl[bk];
            if (g < (bk + 1) * CAPB) ebuf[g] = pp & 0x3FFFFFu;  // col | rl<<16
        }
    }
}

// --- block-per-bucket: two-pass LDS counting sort (no reg staging), then
//     R16-exact shfl gather. xlb = y = dis*xl. out = dis_i*(y_i + sum y_c).
__global__ __launch_bounds__(512) void k_sortred4(
        const int* __restrict__ bcur, const unsigned* __restrict__ ebuf,
        const float* __restrict__ dis, const unsigned short* __restrict__ xlb,
        float* __restrict__ out, int N) {
    __shared__ unsigned short sorted[CAPB];     // 8 KB
    __shared__ int cnt[RPB];
    __shared__ int excl[RPB];
    __shared__ int cur[RPB];
    const int t = threadIdx.x, b = blockIdx.x;
    const int ebase = b * CAPB;
    int mb = bcur[b] - ebase;
    if (mb > CAPB) mb = CAPB;
    if (mb < 0) mb = 0;

    if (t < RPB) cnt[t] = 0;
    __syncthreads();
    for (int i = t; i < mb; i += 512)           // pass 1: count (streaming)
        atomicAdd(&cnt[(ebuf[ebase + i] >> 16) & 63], 1);
    __syncthreads();
    if (t < 64) {                               // 64-key wave scan
        int v = cnt[t], inc = v;
        #pragma unroll
        for (int off = 1; off < 64; off <<= 1) { int o = __shfl_up(inc, off); if (t >= off) inc += o; }
        excl[t] = inc - v;
        cur[t]  = inc - v;
    }
    __syncthreads();
    for (int i = t; i < mb; i += 512) {         // pass 2: scatter (L2-hit)
        unsigned pp = ebuf[ebase + i];
        int pos = atomicAdd(&cur[(pp >> 16) & 63], 1);
        sorted[pos] = (unsigned short)(pp & 0xFFFFu);
    }
    __syncthreads();

    const int wv = t >> 6, lane = t & 63;
    const int half = lane >> 5, l32 = lane & 31;

#define FETCH(V, J) do { \
    _Pragma("unroll") \
    for (int u = 0; u < 8; ++u) { \
        int cc = __shfl(c, (J) + 2 * u + half); \
        V[u] = *(const us4*)&xlb[((size_t)cc << 7) + (l32 << 2)]; \
    } } while (0)
#define CFULL(V) do { \
    _Pragma("unroll") \
    for (int u = 0; u < 8; ++u) { \
        a0 += bf2f(V[u][0]); a1 += bf2f(V[u][1]); \
        a2 += bf2f(V[u][2]); a3 += bf2f(V[u][3]); \
    } } while (0)
#define CTAIL(V, J) do { \
    _Pragma("unroll") \
    for (int u = 0; u < 8; ++u) { \
        float w = ((J) + 2 * u + half < mm) ? 1.0f : 0.0f; \
        a0 = fmaf(w, bf2f(V[u][0]), a0); a1 = fmaf(w, bf2f(V[u][1]), a1); \
        a2 = fmaf(w, bf2f(V[u][2]), a2); a3 = fmaf(w, bf2f(V[u][3]), a3); \
    } } while (0)

    // gather: wave wv owns rows wv*8 .. wv*8+7
    for (int r8 = 0; r8 < 8; ++r8) {
        const int rl = wv * 8 + r8;
        const int grow = b * RPB + rl;
        if (grow >= N) break;
        const int beg = excl[rl], end = cur[rl];
        // self loop: y[i]; only half 0 contributes (halves summed at end)
        us4 sv = *(const us4*)&xlb[(size_t)grow * D + (l32 << 2)];
        float s = (half == 0) ? 1.0f : 0.0f;
        float a0 = s * bf2f(sv[0]), a1 = s * bf2f(sv[1]);
        float a2 = s * bf2f(sv[2]), a3 = s * bf2f(sv[3]);
        for (int bs = beg; bs < end; bs += 64) {
            int mm = end - bs; if (mm > 64) mm = 64;
            int c = 0;
            if (lane < mm) c = sorted[bs + lane];
            us4 A[8], B[8];
            int j = 0;
            FETCH(A, 0);
            for (; j + 32 <= mm; j += 32) {
                FETCH(B, j + 16);               // issue next before consuming A
                CFULL(A);
                if (j + 32 < mm) FETCH(A, j + 32);
                CFULL(B);
            }
            int rem = mm - j;                   // 0 < rem < 32 => A fetched at j
            if (rem > 0) {
                if (rem > 16) { FETCH(B, j + 16); CFULL(A); CTAIL(B, j + 16); }
                else          { CTAIL(A, j); }
            }
        }
        a0 += __shfl_xor(a0, 32);
        a1 += __shfl_xor(a1, 32);
        a2 += __shfl_xor(a2, 32);
        a3 += __shfl_xor(a3, 32);
        if (half == 0) {
            const float di = dis[grow];
            *(float4*)&out[(size_t)grow * D + (l32 << 2)] =
                make_float4(di * a0, di * a1, di * a2, di * a3);
        }
    }
#undef FETCH
#undef CFULL
#undef CTAIL
}

// ======================= fallback (R1 atomic path) =======================
__global__ __launch_bounds__(256) void k_zero(int* __restrict__ p, int n) {
    int i = blockIdx.x * 256 + threadIdx.x;
    if (i < n) p[i] = 0;
}
__global__ __launch_bounds__(256) void k_deg(const int* __restrict__ cols,
                                             int* __restrict__ cntc, int E) {
    int e = blockIdx.x * 256 + threadIdx.x;
    if (e < E) atomicAdd(&cntc[cols[e]], 1);
}
__global__ __launch_bounds__(256) void k_dis(const int* __restrict__ cntc,
                                             float* __restrict__ dis, int N) {
    int i = blockIdx.x * 256 + threadIdx.x;
    if (i < N) dis[i] = rsqrtf((float)(cntc[i] + 1));
}
#define GEMM_R 8
__global__ __launch_bounds__(128) void k_gemmf(const float* __restrict__ x,
                                               const float* __restrict__ W,
                                               const float* __restrict__ b,
                                               float* __restrict__ xl, int N) {
    __shared__ float xs[GEMM_R][D];
    const int c  = threadIdx.x;
    const int r0 = blockIdx.x * GEMM_R;
    #pragma unroll
    for (int r = 0; r < GEMM_R; ++r) {
        int row = r0 + r;
        xs[r][c] = (row < N) ? x[row * D + c] : 0.0f;
    }
    __syncthreads();
    float acc[GEMM_R];
    const float bc = b[c];
    #pragma unroll
    for (int r = 0; r < GEMM_R; ++r) acc[r] = bc;
    for (int k = 0; k < D; k += 4) {
        const float w0 = W[(k + 0) * D + c];
        const float w1 = W[(k + 1) * D + c];
        const float w2 = W[(k + 2) * D + c];
        const float w3 = W[(k + 3) * D + c];
        #pragma unroll
        for (int r = 0; r < GEMM_R; ++r) {
            const float4 xv = *reinterpret_cast<const float4*>(&xs[r][k]);
            acc[r] = fmaf(xv.x, w0, acc[r]);
            acc[r] = fmaf(xv.y, w1, acc[r]);
            acc[r] = fmaf(xv.z, w2, acc[r]);
            acc[r] = fmaf(xv.w, w3, acc[r]);
        }
    }
    #pragma unroll
    for (int r = 0; r < GEMM_R; ++r) {
        int row = r0 + r;
        if (row < N) xl[row * D + c] = acc[r];
    }
}
__global__ __launch_bounds__(256) void k_self(const float* __restrict__ xl,
                                              const float* __restrict__ dis,
                                              float* __restrict__ out, int N) {
    int gid = blockIdx.x * 256 + threadIdx.x;
    int i = gid >> 7;
    if (i < N) {
        float d = dis[i];
        out[gid] = d * d * xl[gid];
    }
}
__global__ __launch_bounds__(256) void k_scatter(const int* __restrict__ rows,
                                                 const int* __restrict__ cols,
                                                 const float* __restrict__ dis,
                                                 const float* __restrict__ xl,
                                                 float* __restrict__ out, int E) {
    long long gid = (long long)blockIdx.x * 256 + threadIdx.x;
    int e    = (int)(gid >> 6);
    int lane = (int)(gid & 63);
    if (e >= E) return;
    const int row = rows[e];
    const int col = cols[e];
    const float nrm = dis[row] * dis[col];
    atomicAdd(&out[row * D + lane],      nrm * xl[col * D + lane]);
    atomicAdd(&out[row * D + 64 + lane], nrm * xl[col * D + 64 + lane]);
}

// ======================= launch ==========================================
extern "C" void kernel_launch(void* const* d_in, const int* in_sizes, int n_in,
                              void* d_out, int out_size, void* d_ws, size_t ws_size,
                              hipStream_t stream) {
    const float* x   = (const float*)d_in[0];
    const int*   ei  = (const int*)d_in[1];
    const float* W   = (const float*)d_in[2];
    const float* b   = (const float*)d_in[3];
    float*       out = (float*)d_out;

    const int N = in_sizes[0] / D;   // 50000
    const int E = in_sizes[1] / 2;   // 1.6M
    const int* rows = ei;
    const int* cols = ei + E;
    const int NBK = (N + RPB - 1) / RPB;       // 782 buckets of 64 rows
    const int NT  = (E + TILE - 1) / TILE;     // 196 bin blocks
    const int GN  = (N + 63) / 64;             // 782 gemm blocks
    const int NW  = (N + 3) / 4;               // 12500 histogram words

    // ws layout
    char* p = (char*)d_ws;
    size_t off = 0;
    unsigned short* xlb     = (unsigned short*)(p + off); off += (size_t)N * D * 2;
    unsigned short* wtb     = (unsigned short*)(p + off); off += (size_t)D * D * 2;
    float*          dis     = (float*)(p + off);          off += (size_t)N * 4;
    int*            bcur    = (int*)(p + off);            off += (size_t)MAXBK * 4;
    unsigned*       ebuf    = (unsigned*)(p + off);       off += (size_t)NBK * CAPB * 4;
    unsigned*       phist   = (unsigned*)(p + off);       off += (size_t)NH * NW * 4;

    const int gN = (N + 255) / 256;
    const int gE = (E + 255) / 256;

    if (N <= 65536 && NBK <= 800 && ws_size >= off) {
        int gP = (D * D + 255) / 256;
        if (gP < (NBK + 255) / 256) gP = (NBK + 255) / 256;
        k_prep     <<<gP, 256, 0, stream>>>(W, wtb, bcur, NBK);
        k_hist     <<<NH, 1024, 0, stream>>>(cols, phist, E, NW);
        k_dismerge <<<(NW + 255) / 256, 256, 0, stream>>>(phist, dis, N, NW);
        k_bin      <<<NT, BINB, 0, stream>>>(rows, cols, bcur, ebuf, E, NBK);
        k_gemm     <<<GN, 1024, 0, stream>>>(x, wtb, b, dis, xlb, N);
        k_sortred4 <<<NBK, 512, 0, stream>>>(bcur, ebuf, dis, xlb, out, N);
    } else {
        // fallback: R1 atomic scatter path (fp32 xl)
        char* q = (char*)d_ws;
        float* xl   = (float*)q;
        float* disF = (float*)(q + (size_t)N * D * 4);
        int*   cc   = (int*)(q + (size_t)N * D * 4 + (size_t)N * 4);
        k_zero <<<gN, 256, 0, stream>>>(cc, N);
        k_deg  <<<gE, 256, 0, stream>>>(cols, cc, E);
        k_dis  <<<gN, 256, 0, stream>>>(cc, disF, N);
        k_gemmf<<<(N + GEMM_R - 1) / GEMM_R, 128, 0, stream>>>(x, W, b, xl, N);
        k_self <<<((N * D) + 255) / 256, 256, 0, stream>>>(xl, disF, out, N);
        long long st = (long long)E * 64;
        k_scatter<<<(int)((st + 255) / 256), 256, 0, stream>>>(rows, cols, disF, xl, out, E);
    }
}

// Round 9
// 181.441 us; speedup vs baseline: 1.2593x; 1.0195x over previous
//
#include <hip/hip_runtime.h>
#include <hip/hip_bf16.h>

// GCNConv: out[i] = sum_{e: row[e]=i} dis[row]*dis[col]*xl[col] + dis[i]^2*xl[i]
// N=50000, E=1.6M, D=128, fp32 in/out.
//
// R23 -> R24: splitting bin/gemm/hist (R23) lost concurrency: k_bin alone is
// 196 big blocks (<1/CU) of barrier-separated phases - pure latency. R21's
// fused 3-way kernel did all three jobs in <=79us. Restore it:
//  - k_trijoint: blocks [0,NT) bin | [NT,NT+GN) gemm (NO premul -> no dis
//    dependency) | [NT+GN,+NH) hist. 1234 independent blocks fill the chip.
//  - k_dismerge: phist -> dis.  k_disy (R20-verified): y = dis*xl in place.
//  - k_sortred4: byte-identical to R23 (63us, VGPR 48, FETCH 150MB floor).

#define D     128
#define TILE  8192
#define BINB  1024      // block size
#define RPB   64        // rows per bucket
#define CAPB  4096      // ebuf capacity per bucket (mean 2046, ~45 sigma)
#define NH    256       // histogram blocks

typedef short  bf16x8 __attribute__((ext_vector_type(8)));
typedef float  f32x4  __attribute__((ext_vector_type(4)));
typedef unsigned short us4 __attribute__((ext_vector_type(4)));
typedef unsigned short us8 __attribute__((ext_vector_type(8)));

static __device__ __forceinline__ unsigned short f2bf(float f) {
    unsigned u = __float_as_uint(f);
    u = (u + 0x7FFFu + ((u >> 16) & 1u)) >> 16;   // RNE
    return (unsigned short)u;
}
static __device__ __forceinline__ float bf2f(unsigned short s) {
    return __uint_as_float(((unsigned)s) << 16);
}

// --- init: bcur[b]=b*CAPB, wtb = bf16(W^T) -------------------------------
__global__ __launch_bounds__(256) void k_prep(const float* __restrict__ W,
                                              unsigned short* __restrict__ wtb,
                                              int* __restrict__ bcur,
                                              int NBK) {
    int i = blockIdx.x * 256 + threadIdx.x;
    if (i < NBK) bcur[i] = i * CAPB;
    if (i < D * D) {
        int n = i >> 7, k = i & 127;
        wtb[n * 128 + k] = f2bf(W[k * 128 + n]);
    }
}

// --- fused 3-way kernel --------------------------------------------------
__global__ __launch_bounds__(1024) void k_trijoint(
        const int* __restrict__ rows, const int* __restrict__ cols,
        int* __restrict__ bcur, unsigned* __restrict__ ebuf,
        const float* __restrict__ x, const unsigned short* __restrict__ wtb,
        const float* __restrict__ bia, unsigned short* __restrict__ xlb,
        unsigned* __restrict__ phist,
        int E, int N, int NBK, int NT, int GN, int NW) {
    __shared__ __align__(16) unsigned char smem[65536];
    const int t = threadIdx.x;

    if ((int)blockIdx.x >= NT + GN) {
        // ---------------- hist path: LDS byte-packed partial histogram ---
        unsigned* hist = (unsigned*)smem;               // NW words <= 16384
        for (int w = t; w < NW; w += BINB) hist[w] = 0;
        __syncthreads();
        const int hb   = (int)blockIdx.x - NT - GN;
        const int SEG  = (E + NH - 1) / NH;
        const int hbeg = hb * SEG;
        int hend = hbeg + SEG; if (hend > E) hend = E;
        for (int i = hbeg + t; i < hend; i += BINB) {
            unsigned c = (unsigned)cols[i];
            atomicAdd(&hist[c >> 2], 1u << ((c & 3u) * 8u));
        }
        __syncthreads();
        unsigned* dst = phist + (size_t)hb * NW;
        for (int w = t; w < NW; w += BINB) dst[w] = hist[w];
        return;
    }

    if ((int)blockIdx.x >= NT) {
        // ---------------- gemm path: 64x128 tile, no premul --------------
        unsigned short (*wt)[136] = (unsigned short (*)[136])smem;            // 34816 B
        unsigned short (*xs)[136] = (unsigned short (*)[136])(smem + 34816);  // 17408 B
        unsigned short (*ys)[128] = (unsigned short (*)[128])smem;            // 16384 B (over wt)
        const int row0 = ((int)blockIdx.x - NT) * 64;
        #pragma unroll
        for (int i = 0; i < 2; ++i) {         // W^T: 2048 ushort8 chunks
            int j = i * 1024 + t;
            int n = j >> 4, k8 = j & 15;
            us8 v = *(const us8*)&wtb[j * 8];
            *(us8*)&wt[n][k8 * 8] = v;
        }
        #pragma unroll
        for (int i = 0; i < 2; ++i) {         // x: 2048 float4 -> ushort4
            int j = i * 1024 + t;
            int r = j >> 5, c4 = j & 31;
            int gr = row0 + r;
            us4 o = (us4){0, 0, 0, 0};
            if (gr < N) {
                float4 v = *(const float4*)&x[(size_t)gr * D + c4 * 4];
                o = (us4){f2bf(v.x), f2bf(v.y), f2bf(v.z), f2bf(v.w)};
            }
            *(us4*)&xs[r][c4 * 4] = o;
        }
        __syncthreads();
        f32x4 acc[8];
        if (t < 256) {
            const int w  = t >> 6, l = t & 63;
            const int m0 = w * 16;
            const int lm = l & 15, lq = l >> 4;
            #pragma unroll
            for (int nt = 0; nt < 8; ++nt) acc[nt] = (f32x4){0.f, 0.f, 0.f, 0.f};
            #pragma unroll
            for (int kk = 0; kk < 4; ++kk) {
                const int kof = kk * 32 + lq * 8;
                bf16x8 a = *(const bf16x8*)&xs[m0 + lm][kof];
                #pragma unroll
                for (int nt = 0; nt < 8; ++nt) {
                    bf16x8 bb = *(const bf16x8*)&wt[nt * 16 + lm][kof];
                    acc[nt] = __builtin_amdgcn_mfma_f32_16x16x32_bf16(a, bb, acc[nt], 0, 0, 0);
                }
            }
        }
        __syncthreads();                      // all wt/xs reads complete
        if (t < 256) {
            const int w  = t >> 6, l = t & 63;
            const int m0 = w * 16;
            const int lm = l & 15, lq = l >> 4;
            float bc[8];
            #pragma unroll
            for (int nt = 0; nt < 8; ++nt) bc[nt] = bia[nt * 16 + lm];
            #pragma unroll
            for (int r = 0; r < 4; ++r) {
                int lrow = m0 + lq * 4 + r;
                #pragma unroll
                for (int nt = 0; nt < 8; ++nt)
                    ys[lrow][nt * 16 + lm] = f2bf(acc[nt][r] + bc[nt]);
            }
        }
        __syncthreads();
        {   // coalesced copy-out: 1024 threads x one us8
            int r = t >> 4, e8 = t & 15;
            int grow = row0 + r;
            if (grow < N)
                *(us8*)&xlb[(size_t)grow * D + e8 * 8] = *(const us8*)&ys[r][e8 * 8];
        }
        return;
    }

    // ---------------- bin path: row-bucket LDS sort, coalesced writes ----
    unsigned* sorted = (unsigned*)smem;                 // 32768 B
    int* lcnt  = (int*)(smem + 32768);                  // 800 ints each
    int* lbase = lcnt + 800;
    int* excl  = lcnt + 1600;
    int* cur   = lcnt + 2400;                           // ends at 45568 B

    const int base = blockIdx.x * TILE;
    int m = E - base; if (m > TILE) m = TILE;

    unsigned p[TILE / BINB];
    #pragma unroll
    for (int it = 0; it < TILE / BINB; ++it) {
        int i = it * BINB + t;
        if (i < m) {
            unsigned r = (unsigned)rows[base + i];
            unsigned c = (unsigned)cols[base + i];
            p[it] = c | ((r & 63u) << 16) | ((r >> 6) << 22);
        }
    }
    if (t < 800) lcnt[t] = 0;
    __syncthreads();
    #pragma unroll
    for (int it = 0; it < TILE / BINB; ++it) {
        int i = it * BINB + t;
        if (i < m) atomicAdd(&lcnt[p[it] >> 22], 1);
    }
    __syncthreads();
    // wave 0: scan buckets, 13 keys/lane; write excl AND cur
    if (t < 64) {
        int v[13], s = 0;
        #pragma unroll
        for (int u = 0; u < 13; ++u) {
            int k = t * 13 + u;
            v[u] = (k < NBK) ? lcnt[k] : 0;
            s += v[u];
        }
        int inc = s;
        #pragma unroll
        for (int off = 1; off < 64; off <<= 1) { int o = __shfl_up(inc, off); if (t >= off) inc += o; }
        int run = inc - s;
        #pragma unroll
        for (int u = 0; u < 13; ++u) {
            int k = t * 13 + u;
            if (k < NBK) { excl[k] = run; cur[k] = run; }
            run += v[u];
        }
    }
    if (t < NBK) {                   // reserve global regions, rotated order
        int tb = t + (int)((blockIdx.x * 331u) % (unsigned)NBK);
        if (tb >= NBK) tb -= NBK;
        int c0 = lcnt[tb];
        lbase[tb] = c0 ? atomicAdd(&bcur[tb], c0) : 0;
    }
    __syncthreads();
    #pragma unroll
    for (int it = 0; it < TILE / BINB; ++it) {   // scatter into LDS (random: free)
        int i = it * BINB + t;
        if (i < m) {
            int pos = atomicAdd(&cur[p[it] >> 22], 1);
            sorted[pos] = p[it];
        }
    }
    __syncthreads();
    #pragma unroll
    for (int it = 0; it < TILE / BINB; ++it) {   // positional coalesced writes
        int i = it * BINB + t;
        if (i < m) {
            unsigned pp = sorted[i];
            int bk = pp >> 22;
            int g  = lbase[bk] + i - excl[bk];
            if (g < (bk + 1) * CAPB) ebuf[g] = pp & 0x3FFFFFu;  // col | rl<<16
        }
    }
}

// --- merge NH partial histograms -> dis = rsqrt(deg+1) -------------------
__global__ __launch_bounds__(256) void k_dismerge(const unsigned* __restrict__ phist,
                                                  float* __restrict__ dis,
                                                  int N, int NW) {
    int w = blockIdx.x * 256 + threadIdx.x;
    if (w >= NW) return;
    unsigned s0 = 0, s1 = 0, s2 = 0, s3 = 0;
    const unsigned* pw = phist + w;
    #pragma unroll 8
    for (int b = 0; b < NH; ++b) {
        unsigned u = pw[(size_t)b * NW];
        s0 += u & 255u;
        s1 += (u >> 8) & 255u;
        s2 += (u >> 16) & 255u;
        s3 += u >> 24;
    }
    int c0 = w * 4;
    float4 o = make_float4(rsqrtf((float)(s0 + 1)), rsqrtf((float)(s1 + 1)),
                           rsqrtf((float)(s2 + 1)), rsqrtf((float)(s3 + 1)));
    if (c0 + 3 < N) {
        *(float4*)&dis[c0] = o;
    } else {
        if (c0     < N) dis[c0]     = o.x;
        if (c0 + 1 < N) dis[c0 + 1] = o.y;
        if (c0 + 2 < N) dis[c0 + 2] = o.z;
        if (c0 + 3 < N) dis[c0 + 3] = o.w;
    }
}

// --- premul xlb in place: y = dis*xl (R20-verified) ----------------------
__global__ __launch_bounds__(256) void k_disy(const float* __restrict__ dis,
                                              unsigned short* __restrict__ xlb,
                                              int N) {
    int i = blockIdx.x * 256 + threadIdx.x;     // one us8 chunk; 16 per row
    if (i >= N * (D / 8)) return;
    int row = i >> 4;
    float dv = dis[row];
    us8 v = *(const us8*)&xlb[(size_t)i * 8];
    us8 o;
    #pragma unroll
    for (int k = 0; k < 8; ++k) o[k] = f2bf(dv * bf2f(v[k]));
    *(us8*)&xlb[(size_t)i * 8] = o;
}

// --- block-per-bucket: two-pass LDS counting sort, then R16-exact shfl
//     gather. xlb holds y = dis*xl. out = dis_i*(y_i + sum y_c). ----------
__global__ __launch_bounds__(512) void k_sortred4(
        const int* __restrict__ bcur, const unsigned* __restrict__ ebuf,
        const float* __restrict__ dis, const unsigned short* __restrict__ xlb,
        float* __restrict__ out, int N) {
    __shared__ unsigned short sorted[CAPB];     // 8 KB
    __shared__ int cnt[RPB];
    __shared__ int excl[RPB];
    __shared__ int cur[RPB];
    const int t = threadIdx.x, b = blockIdx.x;
    const int ebase = b * CAPB;
    int mb = bcur[b] - ebase;
    if (mb > CAPB) mb = CAPB;
    if (mb < 0) mb = 0;

    if (t < RPB) cnt[t] = 0;
    __syncthreads();
    for (int i = t; i < mb; i += 512)           // pass 1: count (streaming)
        atomicAdd(&cnt[(ebuf[ebase + i] >> 16) & 63], 1);
    __syncthreads();
    if (t < 64) {                               // 64-key wave scan
        int v = cnt[t], inc = v;
        #pragma unroll
        for (int off = 1; off < 64; off <<= 1) { int o = __shfl_up(inc, off); if (t >= off) inc += o; }
        excl[t] = inc - v;
        cur[t]  = inc - v;
    }
    __syncthreads();
    for (int i = t; i < mb; i += 512) {         // pass 2: scatter (L2-hit)
        unsigned pp = ebuf[ebase + i];
        int pos = atomicAdd(&cur[(pp >> 16) & 63], 1);
        sorted[pos] = (unsigned short)(pp & 0xFFFFu);
    }
    __syncthreads();

    const int wv = t >> 6, lane = t & 63;
    const int half = lane >> 5, l32 = lane & 31;

#define FETCH(V, J) do { \
    _Pragma("unroll") \
    for (int u = 0; u < 8; ++u) { \
        int cc = __shfl(c, (J) + 2 * u + half); \
        V[u] = *(const us4*)&xlb[((size_t)cc << 7) + (l32 << 2)]; \
    } } while (0)
#define CFULL(V) do { \
    _Pragma("unroll") \
    for (int u = 0; u < 8; ++u) { \
        a0 += bf2f(V[u][0]); a1 += bf2f(V[u][1]); \
        a2 += bf2f(V[u][2]); a3 += bf2f(V[u][3]); \
    } } while (0)
#define CTAIL(V, J) do { \
    _Pragma("unroll") \
    for (int u = 0; u < 8; ++u) { \
        float w = ((J) + 2 * u + half < mm) ? 1.0f : 0.0f; \
        a0 = fmaf(w, bf2f(V[u][0]), a0); a1 = fmaf(w, bf2f(V[u][1]), a1); \
        a2 = fmaf(w, bf2f(V[u][2]), a2); a3 = fmaf(w, bf2f(V[u][3]), a3); \
    } } while (0)

    // gather: wave wv owns rows wv*8 .. wv*8+7
    for (int r8 = 0; r8 < 8; ++r8) {
        const int rl = wv * 8 + r8;
        const int grow = b * RPB + rl;
        if (grow >= N) break;
        const int beg = excl[rl], end = cur[rl];
        // self loop: y[i]; only half 0 contributes (halves summed at end)
        us4 sv = *(const us4*)&xlb[(size_t)grow * D + (l32 << 2)];
        float s = (half == 0) ? 1.0f : 0.0f;
        float a0 = s * bf2f(sv[0]), a1 = s * bf2f(sv[1]);
        float a2 = s * bf2f(sv[2]), a3 = s * bf2f(sv[3]);
        for (int bs = beg; bs < end; bs += 64) {
            int mm = end - bs; if (mm > 64) mm = 64;
            int c = 0;
            if (lane < mm) c = sorted[bs + lane];
            us4 A[8], B[8];
            int j = 0;
            FETCH(A, 0);
            for (; j + 32 <= mm; j += 32) {
                FETCH(B, j + 16);               // issue next before consuming A
                CFULL(A);
                if (j + 32 < mm) FETCH(A, j + 32);
                CFULL(B);
            }
            int rem = mm - j;                   // 0 < rem < 32 => A fetched at j
            if (rem > 0) {
                if (rem > 16) { FETCH(B, j + 16); CFULL(A); CTAIL(B, j + 16); }
                else          { CTAIL(A, j); }
            }
        }
        a0 += __shfl_xor(a0, 32);
        a1 += __shfl_xor(a1, 32);
        a2 += __shfl_xor(a2, 32);
        a3 += __shfl_xor(a3, 32);
        if (half == 0) {
            const float di = dis[grow];
            *(float4*)&out[(size_t)grow * D + (l32 << 2)] =
                make_float4(di * a0, di * a1, di * a2, di * a3);
        }
    }
#undef FETCH
#undef CFULL
#undef CTAIL
}

// ======================= fallback (R1 atomic path) =======================
__global__ __launch_bounds__(256) void k_zero(int* __restrict__ p, int n) {
    int i = blockIdx.x * 256 + threadIdx.x;
    if (i < n) p[i] = 0;
}
__global__ __launch_bounds__(256) void k_deg(const int* __restrict__ cols,
                                             int* __restrict__ cntc, int E) {
    int e = blockIdx.x * 256 + threadIdx.x;
    if (e < E) atomicAdd(&cntc[cols[e]], 1);
}
__global__ __launch_bounds__(256) void k_dis(const int* __restrict__ cntc,
                                             float* __restrict__ dis, int N) {
    int i = blockIdx.x * 256 + threadIdx.x;
    if (i < N) dis[i] = rsqrtf((float)(cntc[i] + 1));
}
#define GEMM_R 8
__global__ __launch_bounds__(128) void k_gemmf(const float* __restrict__ x,
                                               const float* __restrict__ W,
                                               const float* __restrict__ b,
                                               float* __restrict__ xl, int N) {
    __shared__ float xs[GEMM_R][D];
    const int c  = threadIdx.x;
    const int r0 = blockIdx.x * GEMM_R;
    #pragma unroll
    for (int r = 0; r < GEMM_R; ++r) {
        int row = r0 + r;
        xs[r][c] = (row < N) ? x[row * D + c] : 0.0f;
    }
    __syncthreads();
    float acc[GEMM_R];
    const float bc = b[c];
    #pragma unroll
    for (int r = 0; r < GEMM_R; ++r) acc[r] = bc;
    for (int k = 0; k < D; k += 4) {
        const float w0 = W[(k + 0) * D + c];
        const float w1 = W[(k + 1) * D + c];
        const float w2 = W[(k + 2) * D + c];
        const float w3 = W[(k + 3) * D + c];
        #pragma unroll
        for (int r = 0; r < GEMM_R; ++r) {
            const float4 xv = *reinterpret_cast<const float4*>(&xs[r][k]);
            acc[r] = fmaf(xv.x, w0, acc[r]);
            acc[r] = fmaf(xv.y, w1, acc[r]);
            acc[r] = fmaf(xv.z, w2, acc[r]);
            acc[r] = fmaf(xv.w, w3, acc[r]);
        }
    }
    #pragma unroll
    for (int r = 0; r < GEMM_R; ++r) {
        int row = r0 + r;
        if (row < N) xl[row * D + c] = acc[r];
    }
}
__global__ __launch_bounds__(256) void k_self(const float* __restrict__ xl,
                                              const float* __restrict__ dis,
                                              float* __restrict__ out, int N) {
    int gid = blockIdx.x * 256 + threadIdx.x;
    int i = gid >> 7;
    if (i < N) {
        float d = dis[i];
        out[gid] = d * d * xl[gid];
    }
}
__global__ __launch_bounds__(256) void k_scatter(const int* __restrict__ rows,
                                                 const int* __restrict__ cols,
                                                 const float* __restrict__ dis,
                                                 const float* __restrict__ xl,
                                                 float* __restrict__ out, int E) {
    long long gid = (long long)blockIdx.x * 256 + threadIdx.x;
    int e    = (int)(gid >> 6);
    int lane = (int)(gid & 63);
    if (e >= E) return;
    const int row = rows[e];
    const int col = cols[e];
    const float nrm = dis[row] * dis[col];
    atomicAdd(&out[row * D + lane],      nrm * xl[col * D + lane]);
    atomicAdd(&out[row * D + 64 + lane], nrm * xl[col * D + 64 + lane]);
}

// ======================= launch ==========================================
extern "C" void kernel_launch(void* const* d_in, const int* in_sizes, int n_in,
                              void* d_out, int out_size, void* d_ws, size_t ws_size,
                              hipStream_t stream) {
    const float* x   = (const float*)d_in[0];
    const int*   ei  = (const int*)d_in[1];
    const float* W   = (const float*)d_in[2];
    const float* b   = (const float*)d_in[3];
    float*       out = (float*)d_out;

    const int N = in_sizes[0] / D;   // 50000
    const int E = in_sizes[1] / 2;   // 1.6M
    const int* rows = ei;
    const int* cols = ei + E;
    const int NBK = (N + RPB - 1) / RPB;       // 782 buckets of 64 rows
    const int NT  = (E + TILE - 1) / TILE;     // 196 bin blocks
    const int GN  = (N + 63) / 64;             // 782 gemm blocks
    const int NW  = (N + 3) / 4;               // 12500 histogram words

    // ws layout
    char* p = (char*)d_ws;
    size_t off = 0;
    unsigned short* xlb     = (unsigned short*)(p + off); off += (size_t)N * D * 2;
    unsigned short* wtb     = (unsigned short*)(p + off); off += (size_t)D * D * 2;
    float*          dis     = (float*)(p + off);          off += (size_t)N * 4;
    int*            bcur    = (int*)(p + off);            off += (size_t)NBK * 4;
    unsigned*       ebuf    = (unsigned*)(p + off);       off += (size_t)NBK * CAPB * 4;
    unsigned*       phist   = (unsigned*)(p + off);       off += (size_t)NH * NW * 4;

    const int gN = (N + 255) / 256;
    const int gE = (E + 255) / 256;

    if (N <= 65536 && NBK <= 800 && NW <= 16384 && ws_size >= off) {
        int gP = (D * D + 255) / 256;
        if (gP < (NBK + 255) / 256) gP = (NBK + 255) / 256;
        k_prep    <<<gP, 256, 0, stream>>>(W, wtb, bcur, NBK);
        k_trijoint<<<NT + GN + NH, BINB, 0, stream>>>(rows, cols, bcur, ebuf,
                                                      x, wtb, b, xlb, phist,
                                                      E, N, NBK, NT, GN, NW);
        k_dismerge<<<(NW + 255) / 256, 256, 0, stream>>>(phist, dis, N, NW);
        k_disy    <<<(N * (D / 8) + 255) / 256, 256, 0, stream>>>(dis, xlb, N);
        k_sortred4<<<NBK, 512, 0, stream>>>(bcur, ebuf, dis, xlb, out, N);
    } else {
        // fallback: R1 atomic scatter path (fp32 xl)
        char* q = (char*)d_ws;
        float* xl   = (float*)q;
        float* disF = (float*)(q + (size_t)N * D * 4);
        int*   cc   = (int*)(q + (size_t)N * D * 4 + (size_t)N * 4);
        k_zero <<<gN, 256, 0, stream>>>(cc, N);
        k_deg  <<<gE, 256, 0, stream>>>(cols, cc, E);
        k_dis  <<<gN, 256, 0, stream>>>(cc, disF, N);
        k_gemmf<<<(N + GEMM_R - 1) / GEMM_R, 128, 0, stream>>>(x, W, b, xl, N);
        k_self <<<((N * D) + 255) / 256, 256, 0, stream>>>(xl, disF, out, N);
        long long st = (long long)E * 64;
        k_scatter<<<(int)((st + 255) / 256), 256, 0, stream>>>(rows, cols, disF, xl, out, E);
    }
}